// Round 8
// baseline (471.090 us; speedup 1.0000x reference)
//
#include <hip/hip_runtime.h>
#include <hip/hip_bf16.h>
#include <cstdint>

#define DD 8192
#define NROW 200
#define MT 13          // 13 M-tiles of 16 rows = 208
#define MPAD 208
#define KPV 256        // padded K for the PV GEMM
#define EPSV 1e-5f
#define BK 64
#define ABUF_BYTES (MPAD * BK * 2)   // 26624 bytes per LDS A-buffer

using short8 = __attribute__((ext_vector_type(8))) short;
using f32x4  = __attribute__((ext_vector_type(4))) float;

#define MEMBAR asm volatile("" ::: "memory")

__device__ __forceinline__ ushort f2bf(float f) {
    union { float f; unsigned u; } c; c.f = f;
    unsigned u = c.u;
    return (ushort)((u + 0x7FFFu + ((u >> 16) & 1u)) >> 16);  // RNE
}

__device__ __forceinline__ short8 pack8(float4 a, float4 b) {
    short8 o;
    o[0]=f2bf(a.x); o[1]=f2bf(a.y); o[2]=f2bf(a.z); o[3]=f2bf(a.w);
    o[4]=f2bf(b.x); o[5]=f2bf(b.y); o[6]=f2bf(b.z); o[7]=f2bf(b.w);
    return o;
}

// ---------------- kernel 1: x (f32 [200][8192]) -> xb (bf16 [208][8192], pad rows 0)
__global__ void cvt_x(const float* __restrict__ x, ushort* __restrict__ xb) {
    int i = (blockIdx.x * 256 + threadIdx.x) * 8;
    int row = i >> 13;
    int col = i & (DD - 1);
    short8 o;
    if (row < NROW) {
        const float4* p = reinterpret_cast<const float4*>(x + (size_t)row * DD + col);
        float4 a = p[0], b = p[1];
        o = pack8(a, b);
    } else {
        for (int j = 0; j < 8; ++j) o[j] = 0;
    }
    *reinterpret_cast<short8*>(xb + i) = o;
}

// ---------------- kernel 2: fused QKV GEMM, K-split x4, XCD-locality-swizzled.
// 1D grid 768, block 256 (4 waves). Decode: xcd = lin&7 gets contiguous work range
// -> per-XCD A working set <= 2 chunks (1.7 MB), L2-resident.
// Block: 128 N-cols (wave: 2 colgroups), K-chunk 2048, BK=64 LDS dbuf (gl_lds,
// swizzled source), counted vmcnt, 2 raw barriers/phase. 3 blocks/CU, 12 waves/CU.
// Epilogue: acc -> LDS (2 x 104-row halves) -> full-line coalesced fp32 partial
// stores, layout [mat][ks][208][8192].
__global__ __launch_bounds__(256, 3) void qkv_r8(
    const ushort* __restrict__ xb,
    const float* __restrict__ Wq, const float* __restrict__ Wk, const float* __restrict__ Wv,
    float* __restrict__ part)
{
    __shared__ char L[2 * ABUF_BYTES];   // 53,248 B -> 3 blocks/CU; reused by epilogue

    // ---- XCD-contiguous decode
    const int lin = blockIdx.x;
    const int xcd = lin & 7;
    const int rr  = xcd * 96 + (lin >> 3);   // contiguous 96-range per XCD
    const int g   = rr >> 6;                 // 0..11 = (mat, ksp)
    const int cb  = rr & 63;                 // colblock 0..63
    const int mat = g >> 2;
    const int ksp = g & 3;
    const int kbase = ksp * 2048;

    const float* W = (mat == 0) ? Wq : (mat == 1 ? Wk : Wv);

    const int t     = threadIdx.x;
    const int lane  = t & 63;
    const int wave  = t >> 6;
    const int c     = lane & 15;
    const int kgrp  = lane >> 4;
    const int ncol0 = cb * 128 + wave * 32 + c;
    const int ncol1 = ncol0 + 16;

    const float* wp0 = W + (size_t)ncol0 * DD + kgrp * 8;
    const float* wp1 = W + (size_t)ncol1 * DD + kgrp * 8;

    // A staging: linear LDS [208 rows][128B]; swizzled global source so content at
    // (row, slot16B) holds k-slot = slot ^ (row&7). Per gl_lds: 8 rows x 128 B.
    const ushort* sbase = xb + (size_t)(lane >> 3) * DD
                             + (size_t)(((lane & 7) ^ ((lane >> 3) & 7)) * 8);
    const int r0w = (wave < 2) ? wave * 7 : 14 + (wave - 2) * 6;   // 7/7/6/6 rows-groups
    const int sw  = (wave < 2) ? 7 : 6;

    // ds_read: a-frag (m, chunk cidx): row = m*16+c, slot = cidx ^ (c&7)
    const int b0off = c * 128 + ((kgrp ^ (c & 7)) * 16);
    const int b1off = b0off ^ 64;

    f32x4 acc0[MT], acc1[MT];
    #pragma unroll
    for (int m = 0; m < MT; ++m)
        for (int r = 0; r < 4; ++r) { acc0[m][r] = 0.f; acc1[m][r] = 0.f; }

#define STAGE(BOFF, KK) { _Pragma("unroll") for (int q = 0; q < 7; ++q) { if (q < sw) { \
        __builtin_amdgcn_global_load_lds( \
            (const __attribute__((address_space(1))) void*)(sbase + (KK) + (size_t)(r0w + q) * 8 * DD), \
            (__attribute__((address_space(3))) void*)(L + (BOFF) + (r0w + q) * 1024), \
            16, 0, 0); } } }

#define LOADW(d, KK) { \
        d##0 = *reinterpret_cast<const float4*>(wp0 + (KK)); \
        d##1 = *reinterpret_cast<const float4*>(wp0 + (KK) + 4); \
        d##2 = *reinterpret_cast<const float4*>(wp0 + (KK) + 32); \
        d##3 = *reinterpret_cast<const float4*>(wp0 + (KK) + 36); \
        d##4 = *reinterpret_cast<const float4*>(wp1 + (KK)); \
        d##5 = *reinterpret_cast<const float4*>(wp1 + (KK) + 4); \
        d##6 = *reinterpret_cast<const float4*>(wp1 + (KK) + 32); \
        d##7 = *reinterpret_cast<const float4*>(wp1 + (KK) + 36); }

#define COMPUTE(BASE, b00, b01, b10, b11) { \
        _Pragma("unroll") for (int m = 0; m < MT; ++m) { \
            short8 a0 = *reinterpret_cast<const short8*>(L + (BASE) + b0off + m * 2048); \
            acc0[m] = __builtin_amdgcn_mfma_f32_16x16x32_bf16(a0, b00, acc0[m], 0, 0, 0); \
            acc1[m] = __builtin_amdgcn_mfma_f32_16x16x32_bf16(a0, b10, acc1[m], 0, 0, 0); \
            short8 a1 = *reinterpret_cast<const short8*>(L + (BASE) + b1off + m * 2048); \
            acc0[m] = __builtin_amdgcn_mfma_f32_16x16x32_bf16(a1, b01, acc0[m], 0, 0, 0); \
            acc1[m] = __builtin_amdgcn_mfma_f32_16x16x32_bf16(a1, b11, acc1[m], 0, 0, 0); } }

    float4 w0, w1, w2, w3, w4, w5, w6, w7;

    // prologue: W(0) then stage(0) (FIFO: W older than stage)
    LOADW(w, kbase);
    MEMBAR;
    STAGE(0, kbase);
    MEMBAR;

    int k0 = 0;
    #pragma unroll 1
    for (int ph = 0; ph < 2048 / BK; ++ph) {
        // pack W(t): implicit reg-wait drains W(t) (oldest); stage(t) stays outstanding
        short8 b00 = pack8(w0, w1);
        short8 b01 = pack8(w2, w3);
        short8 b10 = pack8(w4, w5);
        short8 b11 = pack8(w6, w7);
        MEMBAR;
        int knext = kbase + ((k0 + BK) & 2047);    // wraps on last phase (dead prefetch)
        LOADW(w, knext);                           // W(t+1)
        MEMBAR;
        STAGE(((ph + 1) & 1) * ABUF_BYTES, knext); // stage(t+1) into other buffer
        MEMBAR;
        // queue: [stage(t):sw, W(t+1):8, stage(t+1):sw] -> retire stage(t)
        if (sw == 7) asm volatile("s_waitcnt vmcnt(15)" ::: "memory");
        else         asm volatile("s_waitcnt vmcnt(14)" ::: "memory");
        asm volatile("s_barrier" ::: "memory");
        COMPUTE((ph & 1) * ABUF_BYTES, b00, b01, b10, b11);
        asm volatile("s_barrier" ::: "memory");
        k0 += BK;
    }
#undef STAGE
#undef LOADW
#undef COMPUTE

    // ---------------- epilogue: acc -> LDS -> coalesced fp32 partial stores
    asm volatile("s_waitcnt vmcnt(0) lgkmcnt(0)" ::: "memory");  // drain dead prefetch into L
    float* Lf = (float*)L;
    float* pp = part + (size_t)(mat * 4 + ksp) * ((size_t)MPAD * DD);
    const int wcol0 = wave * 32 + c;
    const int wcol1 = wcol0 + 16;
    const int lrow  = t >> 5;          // 0..7
    const int c4    = (t & 31) * 4;    // 0..124
    #pragma unroll
    for (int half = 0; half < 2; ++half) {
        asm volatile("s_barrier" ::: "memory");
        #pragma unroll
        for (int m = 0; m < MT; ++m) {
            int rl = m * 16 + kgrp * 4 - half * 104;
            if (rl >= 0 && rl + 3 < 104) {
                #pragma unroll
                for (int r = 0; r < 4; ++r) {
                    Lf[(rl + r) * 128 + wcol0] = acc0[m][r];
                    Lf[(rl + r) * 128 + wcol1] = acc1[m][r];
                }
            }
        }
        asm volatile("s_waitcnt lgkmcnt(0)" ::: "memory");
        asm volatile("s_barrier" ::: "memory");
        #pragma unroll
        for (int p = 0; p < 13; ++p) {
            int row = half * 104 + p * 8 + lrow;
            *reinterpret_cast<float4*>(pp + (size_t)row * DD + cb * 128 + c4) =
                *reinterpret_cast<const float4*>(Lf + (p * 8 + lrow) * 128 + c4);
        }
    }
}

// ---------------- kernel 2b: reduce partials for q,k -> bf16 + bias
__global__ __launch_bounds__(256) void cvt_qk(const float* __restrict__ part,
                                              const float* __restrict__ bq, const float* __restrict__ bk,
                                              ushort* __restrict__ qb, ushort* __restrict__ kb, int ks) {
    const int mat = blockIdx.z;
    const int row = blockIdx.y;
    const int col = blockIdx.x * 2048 + threadIdx.x * 8;
    const float* bias = mat ? bk : bq;
    float s[8];
    {
        const float4 b0 = *reinterpret_cast<const float4*>(bias + col);
        const float4 b1 = *reinterpret_cast<const float4*>(bias + col + 4);
        s[0]=b0.x; s[1]=b0.y; s[2]=b0.z; s[3]=b0.w; s[4]=b1.x; s[5]=b1.y; s[6]=b1.z; s[7]=b1.w;
    }
    const float* pm = part + (size_t)mat * ks * MPAD * DD + (size_t)row * DD + col;
    for (int p = 0; p < ks; ++p) {
        const float4 a0 = *reinterpret_cast<const float4*>(pm + (size_t)p * MPAD * DD);
        const float4 a1 = *reinterpret_cast<const float4*>(pm + (size_t)p * MPAD * DD + 4);
        s[0]+=a0.x; s[1]+=a0.y; s[2]+=a0.z; s[3]+=a0.w; s[4]+=a1.x; s[5]+=a1.y; s[6]+=a1.z; s[7]+=a1.w;
    }
    short8 o;
    for (int j = 0; j < 8; ++j) o[j] = f2bf(s[j]);
    ushort* outb = mat ? kb : qb;
    *reinterpret_cast<short8*>(outb + (size_t)row * DD + col) = o;
}

// ---------------- kernel 2c: reduce V partials + transpose -> vt bf16 [8192][256]
__global__ void vtrans_r(const float* __restrict__ pv, const float* __restrict__ bv,
                         ushort* __restrict__ vt, int ks) {
    __shared__ float lds[64][65];
    const int t  = threadIdx.x;
    const int n0 = blockIdx.x * 64;
    const int k0 = blockIdx.y * 64;
    #pragma unroll
    for (int r = 0; r < 16; ++r) {
        int kl = r * 4 + (t >> 6);
        int nl = t & 63;
        int k  = k0 + kl;
        float v = 0.f;
        if (k < NROW) {
            v = bv[n0 + nl];
            for (int p = 0; p < ks; ++p)
                v += pv[(size_t)p * MPAD * DD + (size_t)k * DD + n0 + nl];
        }
        lds[nl][kl] = v;
    }
    __syncthreads();
    int nl   = t >> 2;
    int koff = (t & 3) * 16;
    short8 o0, o1;
    for (int j = 0; j < 8; ++j) { o0[j] = f2bf(lds[nl][koff + j]); o1[j] = f2bf(lds[nl][koff + 8 + j]); }
    short8* dst = reinterpret_cast<short8*>(vt + (size_t)(n0 + nl) * KPV + k0 + koff);
    dst[0] = o0; dst[1] = o1;
}

// ---------------- kernel 4: s = q @ k^T  (f32 [208][208]); grid (13,13), 4-wave K-split
__global__ __launch_bounds__(256) void sgemm(const ushort* __restrict__ qb, const ushort* __restrict__ kb,
                                             float* __restrict__ sbuf) {
    const int bm = blockIdx.y, bn = blockIdx.x;
    const int lane  = threadIdx.x & 63;
    const int wave  = threadIdx.x >> 6;
    const int col16 = lane & 15, kgrp = lane >> 4;
    const ushort* ap = qb + (size_t)(bm * 16 + col16) * DD + kgrp * 8;
    const ushort* bp = kb + (size_t)(bn * 16 + col16) * DD + kgrp * 8;
    f32x4 acc;
    for (int r = 0; r < 4; ++r) acc[r] = 0.f;
    const int kend = (wave + 1) * 2048;
    for (int k0 = wave * 2048; k0 < kend; k0 += 32) {
        short8 a = *reinterpret_cast<const short8*>(ap + k0);
        short8 b = *reinterpret_cast<const short8*>(bp + k0);
        acc = __builtin_amdgcn_mfma_f32_16x16x32_bf16(a, b, acc, 0, 0, 0);
    }
    __shared__ f32x4 red[4][64];
    red[wave][lane] = acc;
    __syncthreads();
    if (wave == 0) {
        f32x4 s = red[0][lane];
        for (int j = 1; j < 4; ++j) { f32x4 o = red[j][lane]; for (int r = 0; r < 4; ++r) s[r] += o[r]; }
        for (int r = 0; r < 4; ++r)
            sbuf[(size_t)(bm * 16 + kgrp * 4 + r) * MPAD + bn * 16 + col16] = s[r];
    }
}

// ---------------- kernel 5: per-row mean/var(ddof=1) -> sin -> softmax -> P bf16 [208][256] (pads 0)
__global__ __launch_bounds__(256) void rownorm(const float* __restrict__ sbuf, ushort* __restrict__ pb) {
    const int row = blockIdx.x;
    const int t = threadIdx.x;
    if (row >= NROW) { pb[(size_t)row * KPV + t] = 0; return; }
    __shared__ float part[4];
    const int lane = t & 63, wave = t >> 6;
    float x = (t < NROW) ? sbuf[(size_t)row * MPAD + t] : 0.f;

    float s = x;
    for (int m = 32; m; m >>= 1) s += __shfl_xor(s, m, 64);
    if (lane == 0) part[wave] = s;
    __syncthreads();
    float mean = (part[0] + part[1] + part[2] + part[3]) * (1.f / 200.f);

    float d = (t < NROW) ? (x - mean) : 0.f;
    float s2 = d * d;
    for (int m = 32; m; m >>= 1) s2 += __shfl_xor(s2, m, 64);
    __syncthreads();
    if (lane == 0) part[wave] = s2;
    __syncthreads();
    float var = (part[0] + part[1] + part[2] + part[3]) * (1.f / 199.f);

    float inv = 1.f / sqrtf(var + EPSV);
    float y = sinf(d * inv);
    const float inv_cc = 1.f / 90.50966799187809f;   // 1/sqrt(8192)
    float e = (t < NROW) ? expf(y * inv_cc) : 0.f;

    float se = e;
    for (int m = 32; m; m >>= 1) se += __shfl_xor(se, m, 64);
    __syncthreads();
    if (lane == 0) part[wave] = se;
    __syncthreads();
    float tot = part[0] + part[1] + part[2] + part[3];
    pb[(size_t)row * KPV + t] = (t < NROW) ? f2bf(e / tot) : (ushort)0;
}

// ---------------- kernel 6: out = P @ V  via out[m][n] = sum_k P[m][k] * vt[n][k]
__global__ __launch_bounds__(256) void pv_gemm(const ushort* __restrict__ pb, const ushort* __restrict__ vt,
                                               float* __restrict__ out) {
    const int lane  = threadIdx.x & 63;
    const int wave  = threadIdx.x >> 6;
    const int col16 = lane & 15, kgrp = lane >> 4;
    const int ncol  = blockIdx.x * 64 + wave * 16 + col16;
    const ushort* ap = pb + (size_t)col16 * KPV + kgrp * 8;
    const ushort* bp = vt + (size_t)ncol  * KPV + kgrp * 8;
    f32x4 acc[MT];
    for (int m = 0; m < MT; ++m)
        for (int r = 0; r < 4; ++r) acc[m][r] = 0.f;
    for (int k0 = 0; k0 < KPV; k0 += 32) {
        short8 b = *reinterpret_cast<const short8*>(bp + k0);
        #pragma unroll
        for (int m = 0; m < MT; ++m) {
            short8 a = *reinterpret_cast<const short8*>(ap + (size_t)m * 16 * KPV + k0);
            acc[m] = __builtin_amdgcn_mfma_f32_16x16x32_bf16(a, b, acc[m], 0, 0, 0);
        }
    }
    for (int m = 0; m < MT; ++m)
        for (int r = 0; r < 4; ++r) {
            int row = m * 16 + kgrp * 4 + r;
            if (row < NROW) out[(size_t)row * DD + ncol] = acc[m][r];
        }
}

extern "C" void kernel_launch(void* const* d_in, const int* in_sizes, int n_in,
                              void* d_out, int out_size, void* d_ws, size_t ws_size,
                              hipStream_t stream) {
    const float* x  = (const float*)d_in[0];
    const float* Wq = (const float*)d_in[1];
    const float* bq = (const float*)d_in[2];
    const float* Wk = (const float*)d_in[3];
    const float* bk = (const float*)d_in[4];
    const float* Wv = (const float*)d_in[5];
    const float* bv = (const float*)d_in[6];
    float* out = (float*)d_out;

    char* ws = (char*)d_ws;
    ushort* xb   = (ushort*)(ws);                       // 208*8192*2 = 3,407,872
    ushort* qb   = (ushort*)(ws + 3407872);             // 3,407,872
    ushort* kb   = (ushort*)(ws + 6815744);             // 3,407,872
    ushort* vt   = (ushort*)(ws + 10223616);            // 8192*256*2 = 4,194,304
    float*  sbuf = (float*)(ws + 14417920);             // 208*208*4 = 173,056
    ushort* pb   = (ushort*)(ws + 14590976);            // 208*256*2 = 106,496
    float*  part = (float*)(ws + 14697472);             // 3*4*208*8192*4 = 81,788,928

    cvt_x<<<832, 256, 0, stream>>>(x, xb);
    qkv_r8<<<768, 256, 0, stream>>>(xb, Wq, Wk, Wv, part);
    cvt_qk<<<dim3(4, MPAD, 2), 256, 0, stream>>>(part, bq, bk, qb, kb, 4);
    vtrans_r<<<dim3(128, 4), 256, 0, stream>>>(part + (size_t)2 * 4 * MPAD * DD, bv, vt, 4);
    sgemm<<<dim3(13, 13), 256, 0, stream>>>(qb, kb, sbuf);
    rownorm<<<208, 256, 0, stream>>>(sbuf, pb);
    pv_gemm<<<128, 256, 0, stream>>>(pb, vt, out);
}

// Round 9
// 406.898 us; speedup vs baseline: 1.1578x; 1.1578x over previous
//
#include <hip/hip_runtime.h>
#include <hip/hip_bf16.h>
#include <cstdint>

#define DD 8192
#define NROW 200
#define MT 13          // 13 M-tiles of 16 rows = 208
#define MPAD 208
#define KPV 256        // padded K for the PV GEMM
#define EPSV 1e-5f
#define BK 64

using short8 = __attribute__((ext_vector_type(8))) short;
using f32x4  = __attribute__((ext_vector_type(4))) float;

#define MEMBAR asm volatile("" ::: "memory")

__device__ __forceinline__ ushort f2bf(float f) {
    union { float f; unsigned u; } c; c.f = f;
    unsigned u = c.u;
    return (ushort)((u + 0x7FFFu + ((u >> 16) & 1u)) >> 16);  // RNE
}

__device__ __forceinline__ short8 pack8(float4 a, float4 b) {
    short8 o;
    o[0]=f2bf(a.x); o[1]=f2bf(a.y); o[2]=f2bf(a.z); o[3]=f2bf(a.w);
    o[4]=f2bf(b.x); o[5]=f2bf(b.y); o[6]=f2bf(b.z); o[7]=f2bf(b.w);
    return o;
}

// ---------------- kernel 1: x (f32 [200][8192]) -> xb (bf16 [208][8192], pad rows 0)
__global__ void cvt_x(const float* __restrict__ x, ushort* __restrict__ xb) {
    int i = (blockIdx.x * 256 + threadIdx.x) * 8;
    int row = i >> 13;
    int col = i & (DD - 1);
    short8 o;
    if (row < NROW) {
        const float4* p = reinterpret_cast<const float4*>(x + (size_t)row * DD + col);
        float4 a = p[0], b = p[1];
        o = pack8(a, b);
    } else {
        for (int j = 0; j < 8; ++j) o[j] = 0;
    }
    *reinterpret_cast<short8*>(xb + i) = o;
}

// ---------------- kernel 2: fused QKV GEMM — M-split waves, block-shared W via LDS.
// grid 768 = 3 mats x 256 colblocks, block 256 (4 waves). Block: 32 N-cols, ALL 208
// rows, FULL K (no partials). Wave w owns M-tiles {w, w+4, w+8, w+12} (<13).
// W: coop fp32 load (issued 2 phases ahead) -> bf16 pack -> swizzled ds_write into a
// 4 KB dbuf. A: per-fragment bf16 loads straight from global (xb L2-resident).
// One lgkmcnt(0)+s_barrier per phase; NO gl_lds, NO counted vmcnt, NO partials.
// 3 blocks/CU = 12 waves/CU.
__global__ __launch_bounds__(256) void qkv_dir(
    const ushort* __restrict__ xb,
    const float* __restrict__ Wq, const float* __restrict__ Wk, const float* __restrict__ Wv,
    const float* __restrict__ bq, const float* __restrict__ bk, const float* __restrict__ bv,
    ushort* __restrict__ qb, ushort* __restrict__ kb, ushort* __restrict__ vt)
{
    __shared__ char Wl[2][4096];   // [buf][32 cols][8 swizzled 16B k-slots]

    const int bid = blockIdx.x;
    const int mat = bid >> 8;          // 0..2
    const int cb  = bid & 255;         // col-block (32 cols)
    const float* W    = (mat == 0) ? Wq : (mat == 1 ? Wk : Wv);
    const float* bias = (mat == 0) ? bq : (mat == 1 ? bk : bv);

    const int t    = threadIdx.x;
    const int lane = t & 63;
    const int wave = t >> 6;
    const int c    = lane & 15;
    const int kgrp = lane >> 4;
    const int ncol0 = cb * 32 + c;
    const int ncol1 = ncol0 + 16;

    // W coop staging: thread t -> col t>>3 (0..31), k-slot t&7 (8 fp32 each)
    const float* wsrc = W + (size_t)(cb * 32 + (t >> 3)) * DD + (t & 7) * 8;
    const int wbyte = (t >> 3) * 128 + (((t & 7) ^ ((t >> 3) & 7)) * 16);

    // b-frag reads: col=cg*16+c, chunk j slot = (j*4+kgrp) ^ (c&7)
    const int rb0 = c * 128 + (((kgrp)     ^ (c & 7)) * 16);
    const int rb1 = c * 128 + (((4 + kgrp) ^ (c & 7)) * 16);
    // cg1 adds 2048

    // A fragment base pointers (per M-tile), direct from global
    const int mt0 = wave, mt1 = wave + 4, mt2 = wave + 8, mt3 = wave + 12;
    const ushort* a0p = xb + (size_t)(mt0 * 16 + c) * DD + kgrp * 8;
    const ushort* a1p = xb + (size_t)(mt1 * 16 + c) * DD + kgrp * 8;
    const ushort* a2p = xb + (size_t)(mt2 * 16 + c) * DD + kgrp * 8;
    const ushort* a3p = xb + (size_t)(mt3 * 16 + c) * DD + kgrp * 8;   // wave0 only valid
    const bool has3 = (mt3 < MT);

    f32x4 acc00, acc01, acc10, acc11, acc20, acc21, acc30, acc31;
    for (int r = 0; r < 4; ++r) {
        acc00[r]=0.f; acc01[r]=0.f; acc10[r]=0.f; acc11[r]=0.f;
        acc20[r]=0.f; acc21[r]=0.f; acc30[r]=0.f; acc31[r]=0.f;
    }

#define LOADWREG(d, KK) { \
        d##0 = *reinterpret_cast<const float4*>(wsrc + (KK)); \
        d##1 = *reinterpret_cast<const float4*>(wsrc + (KK) + 4); }

#define PHASE(BUF, K0, dfree, dwrite) { \
        /* prefetch W(p+2) into freed regs */ \
        LOADWREG(dfree, ((K0) + 2 * BK) & (DD - 1)); \
        MEMBAR; \
        /* b-frags for this phase from Wl[BUF] */ \
        short8 b00 = *reinterpret_cast<const short8*>(&Wl[BUF][rb0]); \
        short8 b01 = *reinterpret_cast<const short8*>(&Wl[BUF][rb1]); \
        short8 b10 = *reinterpret_cast<const short8*>(&Wl[BUF][2048 + rb0]); \
        short8 b11 = *reinterpret_cast<const short8*>(&Wl[BUF][2048 + rb1]); \
        /* A fragments (global, L2-resident) */ \
        short8 a00 = *reinterpret_cast<const short8*>(a0p + (K0)); \
        short8 a01 = *reinterpret_cast<const short8*>(a0p + (K0) + 32); \
        short8 a10 = *reinterpret_cast<const short8*>(a1p + (K0)); \
        short8 a11 = *reinterpret_cast<const short8*>(a1p + (K0) + 32); \
        short8 a20 = *reinterpret_cast<const short8*>(a2p + (K0)); \
        short8 a21 = *reinterpret_cast<const short8*>(a2p + (K0) + 32); \
        /* write W(p+1) into other buffer (regs loaded last phase) */ \
        *reinterpret_cast<short8*>(&Wl[(BUF) ^ 1][wbyte]) = pack8(dwrite##0, dwrite##1); \
        /* MFMAs */ \
        acc00 = __builtin_amdgcn_mfma_f32_16x16x32_bf16(a00, b00, acc00, 0, 0, 0); \
        acc01 = __builtin_amdgcn_mfma_f32_16x16x32_bf16(a00, b10, acc01, 0, 0, 0); \
        acc00 = __builtin_amdgcn_mfma_f32_16x16x32_bf16(a01, b01, acc00, 0, 0, 0); \
        acc01 = __builtin_amdgcn_mfma_f32_16x16x32_bf16(a01, b11, acc01, 0, 0, 0); \
        acc10 = __builtin_amdgcn_mfma_f32_16x16x32_bf16(a10, b00, acc10, 0, 0, 0); \
        acc11 = __builtin_amdgcn_mfma_f32_16x16x32_bf16(a10, b10, acc11, 0, 0, 0); \
        acc10 = __builtin_amdgcn_mfma_f32_16x16x32_bf16(a11, b01, acc10, 0, 0, 0); \
        acc11 = __builtin_amdgcn_mfma_f32_16x16x32_bf16(a11, b11, acc11, 0, 0, 0); \
        acc20 = __builtin_amdgcn_mfma_f32_16x16x32_bf16(a20, b00, acc20, 0, 0, 0); \
        acc21 = __builtin_amdgcn_mfma_f32_16x16x32_bf16(a20, b10, acc21, 0, 0, 0); \
        acc20 = __builtin_amdgcn_mfma_f32_16x16x32_bf16(a21, b01, acc20, 0, 0, 0); \
        acc21 = __builtin_amdgcn_mfma_f32_16x16x32_bf16(a21, b11, acc21, 0, 0, 0); \
        if (has3) { \
            short8 a30 = *reinterpret_cast<const short8*>(a3p + (K0)); \
            short8 a31 = *reinterpret_cast<const short8*>(a3p + (K0) + 32); \
            acc30 = __builtin_amdgcn_mfma_f32_16x16x32_bf16(a30, b00, acc30, 0, 0, 0); \
            acc31 = __builtin_amdgcn_mfma_f32_16x16x32_bf16(a30, b10, acc31, 0, 0, 0); \
            acc30 = __builtin_amdgcn_mfma_f32_16x16x32_bf16(a31, b01, acc30, 0, 0, 0); \
            acc31 = __builtin_amdgcn_mfma_f32_16x16x32_bf16(a31, b11, acc31, 0, 0, 0); \
        } \
        asm volatile("s_waitcnt lgkmcnt(0)" ::: "memory"); \
        asm volatile("s_barrier" ::: "memory"); }

    float4 wa0, wa1, wb0, wb1;

    // prologue: wa := W(0); wb := W(1); write W(0) -> buf0
    LOADWREG(wa, 0);
    MEMBAR;
    LOADWREG(wb, BK);
    MEMBAR;
    *reinterpret_cast<short8*>(&Wl[0][wbyte]) = pack8(wa0, wa1);   // waits wa
    asm volatile("s_waitcnt lgkmcnt(0)" ::: "memory");
    asm volatile("s_barrier" ::: "memory");

    int k0 = 0;
    #pragma unroll 1
    for (int it = 0; it < DD / (2 * BK); ++it) {
        // even phase p: read buf0, prefetch W(p+2)->wa, write W(p+1)=wb -> buf1
        PHASE(0, k0, wa, wb);
        // odd phase p+1: read buf1, prefetch W(p+3)->wb, write W(p+2)=wa -> buf0
        PHASE(1, k0 + BK, wb, wa);
        k0 += 2 * BK;
    }
#undef PHASE
#undef LOADWREG

    // ---------------- epilogue: direct stores (no partials)
    const float b0v = bias[ncol0];
    const float b1v = bias[ncol1];
#define STORE_TILE(MTV, A0, A1) { \
        if ((MTV) < MT) { \
            if (mat < 2) { \
                ushort* outb = (mat == 0) ? qb : kb; \
                _Pragma("unroll") for (int r = 0; r < 4; ++r) { \
                    int row = (MTV) * 16 + kgrp * 4 + r; \
                    outb[(size_t)row * DD + ncol0] = f2bf(A0[r] + b0v); \
                    outb[(size_t)row * DD + ncol1] = f2bf(A1[r] + b1v); \
                } \
            } else { \
                _Pragma("unroll") for (int r = 0; r < 4; ++r) { \
                    int row = (MTV) * 16 + kgrp * 4 + r; \
                    vt[(size_t)ncol0 * KPV + row] = f2bf(A0[r] + b0v); \
                    vt[(size_t)ncol1 * KPV + row] = f2bf(A1[r] + b1v); \
                } \
            } \
        } }
    STORE_TILE(mt0, acc00, acc01);
    STORE_TILE(mt1, acc10, acc11);
    STORE_TILE(mt2, acc20, acc21);
    STORE_TILE(mt3, acc30, acc31);
#undef STORE_TILE
}

// ---------------- kernel 4: s = q @ k^T  (f32 [208][208]); grid (13,13), 4-wave K-split
__global__ __launch_bounds__(256) void sgemm(const ushort* __restrict__ qb, const ushort* __restrict__ kb,
                                             float* __restrict__ sbuf) {
    const int bm = blockIdx.y, bn = blockIdx.x;
    const int lane  = threadIdx.x & 63;
    const int wave  = threadIdx.x >> 6;
    const int col16 = lane & 15, kgrp = lane >> 4;
    const ushort* ap = qb + (size_t)(bm * 16 + col16) * DD + kgrp * 8;
    const ushort* bp = kb + (size_t)(bn * 16 + col16) * DD + kgrp * 8;
    f32x4 acc;
    for (int r = 0; r < 4; ++r) acc[r] = 0.f;
    const int kend = (wave + 1) * 2048;
    for (int k0 = wave * 2048; k0 < kend; k0 += 32) {
        short8 a = *reinterpret_cast<const short8*>(ap + k0);
        short8 b = *reinterpret_cast<const short8*>(bp + k0);
        acc = __builtin_amdgcn_mfma_f32_16x16x32_bf16(a, b, acc, 0, 0, 0);
    }
    __shared__ f32x4 red[4][64];
    red[wave][lane] = acc;
    __syncthreads();
    if (wave == 0) {
        f32x4 s = red[0][lane];
        for (int j = 1; j < 4; ++j) { f32x4 o = red[j][lane]; for (int r = 0; r < 4; ++r) s[r] += o[r]; }
        for (int r = 0; r < 4; ++r)
            sbuf[(size_t)(bm * 16 + kgrp * 4 + r) * MPAD + bn * 16 + col16] = s[r];
    }
}

// ---------------- kernel 5: per-row mean/var(ddof=1) -> sin -> softmax -> P bf16 [208][256] (pads 0)
__global__ __launch_bounds__(256) void rownorm(const float* __restrict__ sbuf, ushort* __restrict__ pb) {
    const int row = blockIdx.x;
    const int t = threadIdx.x;
    if (row >= NROW) { pb[(size_t)row * KPV + t] = 0; return; }
    __shared__ float part[4];
    const int lane = t & 63, wave = t >> 6;
    float x = (t < NROW) ? sbuf[(size_t)row * MPAD + t] : 0.f;

    float s = x;
    for (int m = 32; m; m >>= 1) s += __shfl_xor(s, m, 64);
    if (lane == 0) part[wave] = s;
    __syncthreads();
    float mean = (part[0] + part[1] + part[2] + part[3]) * (1.f / 200.f);

    float d = (t < NROW) ? (x - mean) : 0.f;
    float s2 = d * d;
    for (int m = 32; m; m >>= 1) s2 += __shfl_xor(s2, m, 64);
    __syncthreads();
    if (lane == 0) part[wave] = s2;
    __syncthreads();
    float var = (part[0] + part[1] + part[2] + part[3]) * (1.f / 199.f);

    float inv = 1.f / sqrtf(var + EPSV);
    float y = sinf(d * inv);
    const float inv_cc = 1.f / 90.50966799187809f;   // 1/sqrt(8192)
    float e = (t < NROW) ? expf(y * inv_cc) : 0.f;

    float se = e;
    for (int m = 32; m; m >>= 1) se += __shfl_xor(se, m, 64);
    __syncthreads();
    if (lane == 0) part[wave] = se;
    __syncthreads();
    float tot = part[0] + part[1] + part[2] + part[3];
    pb[(size_t)row * KPV + t] = (t < NROW) ? f2bf(e / tot) : (ushort)0;
}

// ---------------- kernel 6: out = P @ V  via out[m][n] = sum_k P[m][k] * vt[n][k]
__global__ __launch_bounds__(256) void pv_gemm(const ushort* __restrict__ pb, const ushort* __restrict__ vt,
                                               float* __restrict__ out) {
    const int lane  = threadIdx.x & 63;
    const int wave  = threadIdx.x >> 6;
    const int col16 = lane & 15, kgrp = lane >> 4;
    const int ncol  = blockIdx.x * 64 + wave * 16 + col16;
    const ushort* ap = pb + (size_t)col16 * KPV + kgrp * 8;
    const ushort* bp = vt + (size_t)ncol  * KPV + kgrp * 8;
    f32x4 acc[MT];
    for (int m = 0; m < MT; ++m)
        for (int r = 0; r < 4; ++r) acc[m][r] = 0.f;
    for (int k0 = 0; k0 < KPV; k0 += 32) {
        short8 b = *reinterpret_cast<const short8*>(bp + k0);
        #pragma unroll
        for (int m = 0; m < MT; ++m) {
            short8 a = *reinterpret_cast<const short8*>(ap + (size_t)m * 16 * KPV + k0);
            acc[m] = __builtin_amdgcn_mfma_f32_16x16x32_bf16(a, b, acc[m], 0, 0, 0);
        }
    }
    for (int m = 0; m < MT; ++m)
        for (int r = 0; r < 4; ++r) {
            int row = m * 16 + kgrp * 4 + r;
            if (row < NROW) out[(size_t)row * DD + ncol] = acc[m][r];
        }
}

extern "C" void kernel_launch(void* const* d_in, const int* in_sizes, int n_in,
                              void* d_out, int out_size, void* d_ws, size_t ws_size,
                              hipStream_t stream) {
    const float* x  = (const float*)d_in[0];
    const float* Wq = (const float*)d_in[1];
    const float* bq = (const float*)d_in[2];
    const float* Wk = (const float*)d_in[3];
    const float* bk = (const float*)d_in[4];
    const float* Wv = (const float*)d_in[5];
    const float* bv = (const float*)d_in[6];
    float* out = (float*)d_out;

    char* ws = (char*)d_ws;
    ushort* xb   = (ushort*)(ws);                       // 208*8192*2 = 3,407,872
    ushort* qb   = (ushort*)(ws + 3407872);             // 3,407,872
    ushort* kb   = (ushort*)(ws + 6815744);             // 3,407,872
    ushort* vt   = (ushort*)(ws + 10223616);            // 8192*256*2 = 4,194,304
    float*  sbuf = (float*)(ws + 14417920);             // 208*208*4 = 173,056
    ushort* pb   = (ushort*)(ws + 14590976);            // 208*256*2 = 106,496
    // total 14,697,472 bytes

    cvt_x<<<832, 256, 0, stream>>>(x, xb);
    qkv_dir<<<768, 256, 0, stream>>>(xb, Wq, Wk, Wv, bq, bk, bv, qb, kb, vt);
    sgemm<<<dim3(13, 13), 256, 0, stream>>>(qb, kb, sbuf);
    rownorm<<<208, 256, 0, stream>>>(sbuf, pb);
    pv_gemm<<<128, 256, 0, stream>>>(pb, vt, out);
}

// Round 10
// 372.661 us; speedup vs baseline: 1.2641x; 1.0919x over previous
//
#include <hip/hip_runtime.h>
#include <hip/hip_bf16.h>
#include <cstdint>

#define DD 8192
#define NROW 200
#define MT 13          // 13 M-tiles of 16 rows = 208
#define MPAD 208
#define KPV 256        // padded K for the PV GEMM
#define EPSV 1e-5f
#define BK 64

using short8 = __attribute__((ext_vector_type(8))) short;
using f32x4  = __attribute__((ext_vector_type(4))) float;

#define MEMBAR asm volatile("" ::: "memory")

__device__ __forceinline__ ushort f2bf(float f) {
    union { float f; unsigned u; } c; c.f = f;
    unsigned u = c.u;
    return (ushort)((u + 0x7FFFu + ((u >> 16) & 1u)) >> 16);  // RNE
}

__device__ __forceinline__ short8 pack8(float4 a, float4 b) {
    short8 o;
    o[0]=f2bf(a.x); o[1]=f2bf(a.y); o[2]=f2bf(a.z); o[3]=f2bf(a.w);
    o[4]=f2bf(b.x); o[5]=f2bf(b.y); o[6]=f2bf(b.z); o[7]=f2bf(b.w);
    return o;
}

// ---------------- kernel 1: x (f32 [200][8192]) -> xb (bf16 [208][8192], pad rows 0)
__global__ void cvt_x(const float* __restrict__ x, ushort* __restrict__ xb) {
    int i = (blockIdx.x * 256 + threadIdx.x) * 8;
    int row = i >> 13;
    int col = i & (DD - 1);
    short8 o;
    if (row < NROW) {
        const float4* p = reinterpret_cast<const float4*>(x + (size_t)row * DD + col);
        float4 a = p[0], b = p[1];
        o = pack8(a, b);
    } else {
        for (int j = 0; j < 8; ++j) o[j] = 0;
    }
    *reinterpret_cast<short8*>(xb + i) = o;
}

// ---------------- kernel 2: fused QKV GEMM — M-split waves, W via 4KB LDS dbuf,
// A register-prefetched ONE FULL PHASE ahead (fix of R9's in-phase A latency).
// grid 768 = 3 mats x 256 colblocks, block 256 (4 waves). Block: 32 N-cols, all 208
// rows, full K, no partials. Wave w owns M-tiles {w, w+4, w+8, w+12} (<13).
// Pipeline slack: A = 1 phase, W-global = 2 phases, W-LDS = 1 phase.
// One lgkmcnt(0)+s_barrier per phase. 3 blocks/CU = 12 waves/CU.
__global__ __launch_bounds__(256) void qkv_dir2(
    const ushort* __restrict__ xb,
    const float* __restrict__ Wq, const float* __restrict__ Wk, const float* __restrict__ Wv,
    const float* __restrict__ bq, const float* __restrict__ bk, const float* __restrict__ bv,
    ushort* __restrict__ qb, ushort* __restrict__ kb, ushort* __restrict__ vt)
{
    __shared__ char Wl[2][4096];   // [buf][32 cols][8 swizzled 16B k-slots]

    const int bid = blockIdx.x;
    const int mat = bid >> 8;          // 0..2
    const int cb  = bid & 255;         // col-block (32 cols)
    const float* W    = (mat == 0) ? Wq : (mat == 1 ? Wk : Wv);
    const float* bias = (mat == 0) ? bq : (mat == 1 ? bk : bv);

    const int t    = threadIdx.x;
    const int lane = t & 63;
    const int wave = t >> 6;
    const int c    = lane & 15;
    const int kgrp = lane >> 4;
    const int ncol0 = cb * 32 + c;
    const int ncol1 = ncol0 + 16;

    // W coop staging: thread t -> col t>>3 (0..31), k-slot t&7 (8 fp32 each)
    const float* wsrc = W + (size_t)(cb * 32 + (t >> 3)) * DD + (t & 7) * 8;
    const int wbyte = (t >> 3) * 128 + (((t & 7) ^ ((t >> 3) & 7)) * 16);

    // b-frag reads: col c, chunk j slot = (j*4+kgrp) ^ (c&7); cg1 adds 2048
    const int rb0 = c * 128 + (((kgrp)     ^ (c & 7)) * 16);
    const int rb1 = c * 128 + (((4 + kgrp) ^ (c & 7)) * 16);

    // A fragment base pointers (per M-tile), direct from global (L2-resident xb)
    const int mt0 = wave, mt1 = wave + 4, mt2 = wave + 8, mt3 = wave + 12;
    const ushort* a0p = xb + (size_t)(mt0 * 16 + c) * DD + kgrp * 8;
    const ushort* a1p = xb + (size_t)(mt1 * 16 + c) * DD + kgrp * 8;
    const ushort* a2p = xb + (size_t)(mt2 * 16 + c) * DD + kgrp * 8;
    const ushort* a3p = xb + (size_t)(mt3 * 16 + c) * DD + kgrp * 8;   // wave0 only
    const bool has3 = (mt3 < MT);

    f32x4 acc00, acc01, acc10, acc11, acc20, acc21, acc30, acc31;
    for (int r = 0; r < 4; ++r) {
        acc00[r]=0.f; acc01[r]=0.f; acc10[r]=0.f; acc11[r]=0.f;
        acc20[r]=0.f; acc21[r]=0.f; acc30[r]=0.f; acc31[r]=0.f;
    }

    // two named A-prefetch sets (static indexing only — rule #20)
    short8 aE0, aE1, aE2, aE3, aE4, aE5, aE6, aE7;
    short8 aO0, aO1, aO2, aO3, aO4, aO5, aO6, aO7;
    float4 wa0, wa1, wb0, wb1;

#define ALOADM(S, KK) { \
        S##0 = *reinterpret_cast<const short8*>(a0p + (KK)); \
        S##1 = *reinterpret_cast<const short8*>(a0p + (KK) + 32); \
        S##2 = *reinterpret_cast<const short8*>(a1p + (KK)); \
        S##3 = *reinterpret_cast<const short8*>(a1p + (KK) + 32); \
        S##4 = *reinterpret_cast<const short8*>(a2p + (KK)); \
        S##5 = *reinterpret_cast<const short8*>(a2p + (KK) + 32); \
        if (has3) { \
            S##6 = *reinterpret_cast<const short8*>(a3p + (KK)); \
            S##7 = *reinterpret_cast<const short8*>(a3p + (KK) + 32); } }

#define LOADWREG(d, KK) { \
        d##0 = *reinterpret_cast<const float4*>(wsrc + (KK)); \
        d##1 = *reinterpret_cast<const float4*>(wsrc + (KK) + 4); }

#define PHASE(BUF, K0, AU, AL, WF, WW) { \
        /* issue A(p+1) into the other set (consumed next phase) */ \
        ALOADM(AL, ((K0) + BK) & (DD - 1)); \
        MEMBAR; \
        /* issue W(p+2) global into freed regs */ \
        LOADWREG(WF, ((K0) + 2 * BK) & (DD - 1)); \
        MEMBAR; \
        /* write W(p+1) (regs loaded 2 phases ago) into other LDS buffer */ \
        *reinterpret_cast<short8*>(&Wl[(BUF) ^ 1][wbyte]) = pack8(WW##0, WW##1); \
        /* b-frags for THIS phase from Wl[BUF] */ \
        short8 b00 = *reinterpret_cast<const short8*>(&Wl[BUF][rb0]); \
        short8 b01 = *reinterpret_cast<const short8*>(&Wl[BUF][rb1]); \
        short8 b10 = *reinterpret_cast<const short8*>(&Wl[BUF][2048 + rb0]); \
        short8 b11 = *reinterpret_cast<const short8*>(&Wl[BUF][2048 + rb1]); \
        /* MFMAs on registers prefetched last phase */ \
        acc00 = __builtin_amdgcn_mfma_f32_16x16x32_bf16(AU##0, b00, acc00, 0, 0, 0); \
        acc01 = __builtin_amdgcn_mfma_f32_16x16x32_bf16(AU##0, b10, acc01, 0, 0, 0); \
        acc00 = __builtin_amdgcn_mfma_f32_16x16x32_bf16(AU##1, b01, acc00, 0, 0, 0); \
        acc01 = __builtin_amdgcn_mfma_f32_16x16x32_bf16(AU##1, b11, acc01, 0, 0, 0); \
        acc10 = __builtin_amdgcn_mfma_f32_16x16x32_bf16(AU##2, b00, acc10, 0, 0, 0); \
        acc11 = __builtin_amdgcn_mfma_f32_16x16x32_bf16(AU##2, b10, acc11, 0, 0, 0); \
        acc10 = __builtin_amdgcn_mfma_f32_16x16x32_bf16(AU##3, b01, acc10, 0, 0, 0); \
        acc11 = __builtin_amdgcn_mfma_f32_16x16x32_bf16(AU##3, b11, acc11, 0, 0, 0); \
        acc20 = __builtin_amdgcn_mfma_f32_16x16x32_bf16(AU##4, b00, acc20, 0, 0, 0); \
        acc21 = __builtin_amdgcn_mfma_f32_16x16x32_bf16(AU##4, b10, acc21, 0, 0, 0); \
        acc20 = __builtin_amdgcn_mfma_f32_16x16x32_bf16(AU##5, b01, acc20, 0, 0, 0); \
        acc21 = __builtin_amdgcn_mfma_f32_16x16x32_bf16(AU##5, b11, acc21, 0, 0, 0); \
        if (has3) { \
            acc30 = __builtin_amdgcn_mfma_f32_16x16x32_bf16(AU##6, b00, acc30, 0, 0, 0); \
            acc31 = __builtin_amdgcn_mfma_f32_16x16x32_bf16(AU##6, b10, acc31, 0, 0, 0); \
            acc30 = __builtin_amdgcn_mfma_f32_16x16x32_bf16(AU##7, b01, acc30, 0, 0, 0); \
            acc31 = __builtin_amdgcn_mfma_f32_16x16x32_bf16(AU##7, b11, acc31, 0, 0, 0); \
        } \
        asm volatile("s_waitcnt lgkmcnt(0)" ::: "memory"); \
        asm volatile("s_barrier" ::: "memory"); }

    // ---------------- prologue: A(0)->aE; wa=W(0); wb=W(1); W(0)->buf0
    ALOADM(aE, 0);
    MEMBAR;
    LOADWREG(wa, 0);
    MEMBAR;
    LOADWREG(wb, BK);
    MEMBAR;
    *reinterpret_cast<short8*>(&Wl[0][wbyte]) = pack8(wa0, wa1);   // waits wa
    asm volatile("s_waitcnt lgkmcnt(0)" ::: "memory");
    asm volatile("s_barrier" ::: "memory");

    int k0 = 0;
    #pragma unroll 1
    for (int it = 0; it < DD / (2 * BK); ++it) {
        // even phase p: consume aE + buf0; load A(p+1)->aO, W(p+2)->wa; write W(p+1)=wb->buf1
        PHASE(0, k0, aE, aO, wa, wb);
        // odd phase p+1: consume aO + buf1; load A(p+2)->aE, W(p+3)->wb; write W(p+2)=wa->buf0
        PHASE(1, k0 + BK, aO, aE, wb, wa);
        k0 += 2 * BK;
    }
#undef PHASE
#undef ALOADM
#undef LOADWREG

    // ---------------- epilogue: direct stores (no partials)
    const float b0v = bias[ncol0];
    const float b1v = bias[ncol1];
#define STORE_TILE(MTV, A0, A1) { \
        if ((MTV) < MT) { \
            if (mat < 2) { \
                ushort* outb = (mat == 0) ? qb : kb; \
                _Pragma("unroll") for (int r = 0; r < 4; ++r) { \
                    int row = (MTV) * 16 + kgrp * 4 + r; \
                    outb[(size_t)row * DD + ncol0] = f2bf(A0[r] + b0v); \
                    outb[(size_t)row * DD + ncol1] = f2bf(A1[r] + b1v); \
                } \
            } else { \
                _Pragma("unroll") for (int r = 0; r < 4; ++r) { \
                    int row = (MTV) * 16 + kgrp * 4 + r; \
                    vt[(size_t)ncol0 * KPV + row] = f2bf(A0[r] + b0v); \
                    vt[(size_t)ncol1 * KPV + row] = f2bf(A1[r] + b1v); \
                } \
            } \
        } }
    STORE_TILE(mt0, acc00, acc01);
    STORE_TILE(mt1, acc10, acc11);
    STORE_TILE(mt2, acc20, acc21);
    STORE_TILE(mt3, acc30, acc31);
#undef STORE_TILE
}

// ---------------- kernel 4: s = q @ k^T  (f32 [208][208]); grid (13,13), 4-wave K-split
__global__ __launch_bounds__(256) void sgemm(const ushort* __restrict__ qb, const ushort* __restrict__ kb,
                                             float* __restrict__ sbuf) {
    const int bm = blockIdx.y, bn = blockIdx.x;
    const int lane  = threadIdx.x & 63;
    const int wave  = threadIdx.x >> 6;
    const int col16 = lane & 15, kgrp = lane >> 4;
    const ushort* ap = qb + (size_t)(bm * 16 + col16) * DD + kgrp * 8;
    const ushort* bp = kb + (size_t)(bn * 16 + col16) * DD + kgrp * 8;
    f32x4 acc;
    for (int r = 0; r < 4; ++r) acc[r] = 0.f;
    const int kend = (wave + 1) * 2048;
    for (int k0 = wave * 2048; k0 < kend; k0 += 32) {
        short8 a = *reinterpret_cast<const short8*>(ap + k0);
        short8 b = *reinterpret_cast<const short8*>(bp + k0);
        acc = __builtin_amdgcn_mfma_f32_16x16x32_bf16(a, b, acc, 0, 0, 0);
    }
    __shared__ f32x4 red[4][64];
    red[wave][lane] = acc;
    __syncthreads();
    if (wave == 0) {
        f32x4 s = red[0][lane];
        for (int j = 1; j < 4; ++j) { f32x4 o = red[j][lane]; for (int r = 0; r < 4; ++r) s[r] += o[r]; }
        for (int r = 0; r < 4; ++r)
            sbuf[(size_t)(bm * 16 + kgrp * 4 + r) * MPAD + bn * 16 + col16] = s[r];
    }
}

// ---------------- kernel 5: per-row mean/var(ddof=1) -> sin -> softmax -> P bf16 [208][256] (pads 0)
__global__ __launch_bounds__(256) void rownorm(const float* __restrict__ sbuf, ushort* __restrict__ pb) {
    const int row = blockIdx.x;
    const int t = threadIdx.x;
    if (row >= NROW) { pb[(size_t)row * KPV + t] = 0; return; }
    __shared__ float part[4];
    const int lane = t & 63, wave = t >> 6;
    float x = (t < NROW) ? sbuf[(size_t)row * MPAD + t] : 0.f;

    float s = x;
    for (int m = 32; m; m >>= 1) s += __shfl_xor(s, m, 64);
    if (lane == 0) part[wave] = s;
    __syncthreads();
    float mean = (part[0] + part[1] + part[2] + part[3]) * (1.f / 200.f);

    float d = (t < NROW) ? (x - mean) : 0.f;
    float s2 = d * d;
    for (int m = 32; m; m >>= 1) s2 += __shfl_xor(s2, m, 64);
    __syncthreads();
    if (lane == 0) part[wave] = s2;
    __syncthreads();
    float var = (part[0] + part[1] + part[2] + part[3]) * (1.f / 199.f);

    float inv = 1.f / sqrtf(var + EPSV);
    float y = sinf(d * inv);
    const float inv_cc = 1.f / 90.50966799187809f;   // 1/sqrt(8192)
    float e = (t < NROW) ? expf(y * inv_cc) : 0.f;

    float se = e;
    for (int m = 32; m; m >>= 1) se += __shfl_xor(se, m, 64);
    __syncthreads();
    if (lane == 0) part[wave] = se;
    __syncthreads();
    float tot = part[0] + part[1] + part[2] + part[3];
    pb[(size_t)row * KPV + t] = (t < NROW) ? f2bf(e / tot) : (ushort)0;
}

// ---------------- kernel 6: out = P @ V  via out[m][n] = sum_k P[m][k] * vt[n][k]
__global__ __launch_bounds__(256) void pv_gemm(const ushort* __restrict__ pb, const ushort* __restrict__ vt,
                                               float* __restrict__ out) {
    const int lane  = threadIdx.x & 63;
    const int wave  = threadIdx.x >> 6;
    const int col16 = lane & 15, kgrp = lane >> 4;
    const int ncol  = blockIdx.x * 64 + wave * 16 + col16;
    const ushort* ap = pb + (size_t)col16 * KPV + kgrp * 8;
    const ushort* bp = vt + (size_t)ncol  * KPV + kgrp * 8;
    f32x4 acc[MT];
    for (int m = 0; m < MT; ++m)
        for (int r = 0; r < 4; ++r) acc[m][r] = 0.f;
    for (int k0 = 0; k0 < KPV; k0 += 32) {
        short8 b = *reinterpret_cast<const short8*>(bp + k0);
        #pragma unroll
        for (int m = 0; m < MT; ++m) {
            short8 a = *reinterpret_cast<const short8*>(ap + (size_t)m * 16 * KPV + k0);
            acc[m] = __builtin_amdgcn_mfma_f32_16x16x32_bf16(a, b, acc[m], 0, 0, 0);
        }
    }
    for (int m = 0; m < MT; ++m)
        for (int r = 0; r < 4; ++r) {
            int row = m * 16 + kgrp * 4 + r;
            if (row < NROW) out[(size_t)row * DD + ncol] = acc[m][r];
        }
}

extern "C" void kernel_launch(void* const* d_in, const int* in_sizes, int n_in,
                              void* d_out, int out_size, void* d_ws, size_t ws_size,
                              hipStream_t stream) {
    const float* x  = (const float*)d_in[0];
    const float* Wq = (const float*)d_in[1];
    const float* bq = (const float*)d_in[2];
    const float* Wk = (const float*)d_in[3];
    const float* bk = (const float*)d_in[4];
    const float* Wv = (const float*)d_in[5];
    const float* bv = (const float*)d_in[6];
    float* out = (float*)d_out;

    char* ws = (char*)d_ws;
    ushort* xb   = (ushort*)(ws);                       // 208*8192*2 = 3,407,872
    ushort* qb   = (ushort*)(ws + 3407872);             // 3,407,872
    ushort* kb   = (ushort*)(ws + 6815744);             // 3,407,872
    ushort* vt   = (ushort*)(ws + 10223616);            // 8192*256*2 = 4,194,304
    float*  sbuf = (float*)(ws + 14417920);             // 208*208*4 = 173,056
    ushort* pb   = (ushort*)(ws + 14590976);            // 208*256*2 = 106,496
    // total 14,697,472 bytes

    cvt_x<<<832, 256, 0, stream>>>(x, xb);
    qkv_dir2<<<768, 256, 0, stream>>>(xb, Wq, Wk, Wv, bq, bk, bv, qb, kb, vt);
    sgemm<<<dim3(13, 13), 256, 0, stream>>>(qb, kb, sbuf);
    rownorm<<<208, 256, 0, stream>>>(sbuf, pb);
    pv_gemm<<<128, 256, 0, stream>>>(pb, vt, out);
}